// Round 8
// baseline (175.932 us; speedup 1.0000x reference)
//
#include <hip/hip_runtime.h>
#include <math.h>

#define LVL 16
#define TBL 65536
#define BATCH 8
#define NPIX 65536       // 256*256
#define SDIM 512
#define HPRIME 2654435761u

typedef __attribute__((ext_vector_type(2))) float f32x2;

struct ResPack { int r[LVL]; };
struct OffPack { int o[LVL]; };   // per-level offset into dense grid (float2 units)

// ws layout (floats): [0, 17152) weff (8 x 2144), [17152, 17920) style (8 x 96),
// [17920, ...) dense grids: per batch GRID_TOT float2 entries.
#define WEFF_STRIDE 2144
#define STYLE_OFF   17152
#define GRIDS_OFF   17920    // floats; float2-aligned

// ---------------------------------------------------------------------------
// Kernel A1: style dots, one wave per (b, v). 768 waves.
// ---------------------------------------------------------------------------
__global__ __launch_bounds__(256) void style_kernel(
    const float* __restrict__ s,
    const float* __restrict__ aw0, const float* __restrict__ ab0,
    const float* __restrict__ aw1, const float* __restrict__ ab1,
    const float* __restrict__ aw2, const float* __restrict__ ab2,
    float* __restrict__ ws)
{
    const int wave_id = blockIdx.x * 4 + ((int)threadIdx.x >> 6);   // [0, 768)
    const int lane    = (int)threadIdx.x & 63;
    const int b = wave_id / 96;
    const int v = wave_id % 96;

    const float* row; float bias;
    if (v < 32)      { row = aw0 + v * SDIM;        bias = ab0[v]; }
    else if (v < 64) { row = aw1 + (v - 32) * SDIM; bias = ab1[v - 32]; }
    else             { row = aw2 + (v - 64) * SDIM; bias = ab2[v - 64]; }

    const float* sb = s + b * SDIM;
    float acc = 0.f;
    #pragma unroll
    for (int j = 0; j < SDIM / 64; ++j) {
        const int k = lane + j * 64;
        acc += sb[k] * row[k];
    }
    #pragma unroll
    for (int off = 32; off >= 1; off >>= 1) acc += __shfl_xor(acc, off, 64);
    if (lane == 0) ws[STYLE_OFF + b * 96 + v] = acc + bias;
}

// ---------------------------------------------------------------------------
// Kernel A2: demod + modulated weights, paired layout (round-7 verified).
// ---------------------------------------------------------------------------
__global__ __launch_bounds__(256) void weff_kernel(
    const float* __restrict__ w0, const float* __restrict__ w1, const float* __restrict__ w2,
    float* __restrict__ ws)
{
    const int b = blockIdx.x;
    __shared__ float st[96];
    __shared__ float demod[67];
    const int tid = (int)threadIdx.x;

    if (tid < 96) st[tid] = ws[STYLE_OFF + b * 96 + tid];
    __syncthreads();

    if (tid < 67) {
        const int o = tid;
        const float* wrow; const float* stp;
        if (o < 32)      { wrow = w0 + o * 32;        stp = st; }
        else if (o < 64) { wrow = w1 + (o - 32) * 32; stp = st + 32; }
        else             { wrow = w2 + (o - 64) * 32; stp = st + 64; }
        float sum = 0.f;
        #pragma unroll
        for (int i = 0; i < 32; ++i) { float v = wrow[i] * stp[i]; sum += v * v; }
        demod[o] = 1.0f / sqrtf(sum + 1e-8f);
    }
    __syncthreads();

    float* outp = ws + b * WEFF_STRIDE;
    for (int idx = tid; idx < 2144; idx += 256) {
        float v;
        if (idx < 1024) {
            const int o2 = idx >> 6, rem = idx & 63, i = rem >> 1, h = rem & 1;
            const int o = o2 + 16 * h;
            v = w0[o * 32 + i] * st[i] * demod[o];
        } else if (idx < 2048) {
            const int j = idx - 1024;
            const int o2 = j >> 6, rem = j & 63, i = rem >> 1, h = rem & 1;
            const int o = o2 + 16 * h;
            v = w1[o * 32 + i] * st[32 + i] * demod[32 + o];
        } else {
            const int j = idx - 2048; const int o = j >> 5, i = j & 31;
            v = w2[j] * st[64 + i] * demod[64 + o];
        }
        outp[idx] = v;
    }
}

// ---------------------------------------------------------------------------
// Kernel C: dense re-gridding. D[b][l][y][x] = table[b][l][hash(x,y)].
// Pure copy (bitwise-identical values); converts hash-scatter into spatially
// local reads for the fused kernel. bid&7 matches fused's XCD mapping so
// batch b's grid is written into XCD b's L2.
// ---------------------------------------------------------------------------
__global__ __launch_bounds__(256) void grid_kernel(
    const float* __restrict__ tables,   // [B, L, T, 2]
    float2* __restrict__ grids,         // [B][GRID_TOT]
    int grid_tot, ResPack res, OffPack off)
{
    const int bid = (int)blockIdx.x;
    const int b = bid & 7;
    const int l = (bid >> 3) & 15;
    const int chunk = bid >> 7;
    const int R = res.r[l];
    const int idx = chunk * 256 + (int)threadIdx.x;
    if (idx >= R * R) return;
    const int y = idx / R;
    const int x = idx - y * R;
    const unsigned h = ((unsigned)x ^ ((unsigned)y * HPRIME)) & 0xFFFFu;
    const float2* tl = (const float2*)(tables + ((size_t)b * LVL + l) * (TBL * 2));
    grids[(size_t)b * grid_tot + off.o[l] + idx] = tl[h];
}

// ---------------------------------------------------------------------------
// Kernel B (dense): XCD-swizzled, 1 px/thread, paired packed-fp32 MLP
// (round-7 verified math), hash gathers replaced by dense-grid bilinear reads.
// ---------------------------------------------------------------------------
__global__ __launch_bounds__(256) void fused_kernel(
    const float2* __restrict__ grids,   // [B][GRID_TOT] dense level grids
    const float* __restrict__ coords,   // [N, 2]
    const float* __restrict__ weff,     // ws: paired weights per batch
    const float* __restrict__ b0, const float* __restrict__ b1, const float* __restrict__ b2,
    float* __restrict__ out,            // [B, 3, 256, 256]
    int grid_tot, ResPack res, OffPack off)
{
    const int b     = blockIdx.x & 7;           // XCD-affinity: batch <-> XCD
    const int chunk = blockIdx.x >> 3;
    const int n     = chunk * 256 + (int)threadIdx.x;

    const float cx = coords[2 * n];
    const float cy = coords[2 * n + 1];
    const float2* gb = grids + (size_t)b * grid_tot;

    float feat[32];
    #pragma unroll
    for (int l = 0; l < LVL; ++l) {
        const int R = res.r[l];
        const float rm1 = (float)(R - 1);
        const float px = cx * rm1, py = cy * rm1;
        const float fpx = floorf(px), fpy = floorf(py);
        const float fx = px - fpx, fy = py - fpy;
        int x0 = (int)fpx, y0 = (int)fpy;
        int x1 = x0 + 1; if (x1 > R - 1) x1 = R - 1;
        int y1 = y0 + 1; if (y1 > R - 1) y1 = R - 1;
        const float2* gl = gb + off.o[l];
        const int ry0 = y0 * R, ry1 = y1 * R;
        const float2 g00 = gl[ry0 + x0];
        const float2 g10 = gl[ry0 + x1];
        const float2 g01 = gl[ry1 + x0];
        const float2 g11 = gl[ry1 + x1];
        const float w00 = (1.f - fx) * (1.f - fy);
        const float w10 = fx * (1.f - fy);
        const float w01 = (1.f - fx) * fy;
        const float w11 = fx * fy;
        feat[2 * l]     = g00.x * w00 + g10.x * w10 + g01.x * w01 + g11.x * w11;
        feat[2 * l + 1] = g00.y * w00 + g10.y * w10 + g01.y * w01 + g11.y * w11;
    }

    const f32x2* W0p = (const f32x2*)(weff + (size_t)b * WEFF_STRIDE);         // [16][32]
    const f32x2* W1p = W0p + 512;                                              // [16][32]
    const float* W2  = weff + (size_t)b * WEFF_STRIDE + 2048;                  // [3][32]

    f32x2 h1p[16];
    #pragma unroll
    for (int o2 = 0; o2 < 16; ++o2) {
        f32x2 acc; acc[0] = b0[o2]; acc[1] = b0[o2 + 16];
        #pragma unroll
        for (int i = 0; i < 32; ++i) {
            f32x2 fb; fb[0] = feat[i]; fb[1] = feat[i];
            acc += W0p[o2 * 32 + i] * fb;
        }
        acc[0] = fmaxf(acc[0], 0.f); acc[1] = fmaxf(acc[1], 0.f);
        h1p[o2] = acc;
    }

    f32x2 h2p[16];
    #pragma unroll
    for (int o2 = 0; o2 < 16; ++o2) {
        f32x2 acc; acc[0] = b1[o2]; acc[1] = b1[o2 + 16];
        #pragma unroll
        for (int i = 0; i < 32; ++i) {
            const float hv = h1p[i & 15][i >> 4];
            f32x2 fb; fb[0] = hv; fb[1] = hv;
            acc += W1p[o2 * 32 + i] * fb;
        }
        acc[0] = fmaxf(acc[0], 0.f); acc[1] = fmaxf(acc[1], 0.f);
        h2p[o2] = acc;
    }

    #pragma unroll
    for (int o = 0; o < 3; ++o) {
        float acc = b2[o];
        #pragma unroll
        for (int i = 0; i < 32; ++i)
            acc = fmaf(W2[o * 32 + i], h2p[i & 15][i >> 4], acc);
        out[((size_t)(b * 3 + o) << 16) + n] = tanhf(acc);
    }
}

// ---------------------------------------------------------------------------
// Fallback (round-7 verified): direct table reads, used only if ws too small.
// ---------------------------------------------------------------------------
__global__ __launch_bounds__(256) void fused_direct(
    const float* __restrict__ tables, const float* __restrict__ coords,
    const float* __restrict__ weff,
    const float* __restrict__ b0, const float* __restrict__ b1, const float* __restrict__ b2,
    float* __restrict__ out, ResPack res)
{
    const int b     = blockIdx.x & 7;
    const int chunk = blockIdx.x >> 3;
    const int n     = chunk * 256 + (int)threadIdx.x;
    const float cx = coords[2 * n];
    const float cy = coords[2 * n + 1];
    const float* tb = tables + (size_t)b * (LVL * TBL * 2);

    float feat[32];
    #pragma unroll
    for (int l = 0; l < LVL; ++l) {
        const int R = res.r[l];
        const float rm1 = (float)(R - 1);
        const float px = cx * rm1, py = cy * rm1;
        const float fpx = floorf(px), fpy = floorf(py);
        const float fx = px - fpx, fy = py - fpy;
        unsigned x0 = (unsigned)fpx, y0 = (unsigned)fpy;
        const unsigned im = (unsigned)(R - 1);
        unsigned x1 = x0 + 1u; if (x1 > im) x1 = im;
        unsigned y1 = y0 + 1u; if (y1 > im) y1 = im;
        const unsigned hy0 = y0 * HPRIME, hy1 = y1 * HPRIME;
        const unsigned h00 = (x0 ^ hy0) & 0xFFFFu;
        const unsigned h10 = (x1 ^ hy0) & 0xFFFFu;
        const unsigned h01 = (x0 ^ hy1) & 0xFFFFu;
        const unsigned h11 = (x1 ^ hy1) & 0xFFFFu;
        const float2* tl = (const float2*)(tb + l * (TBL * 2));
        const float2 g00 = tl[h00];
        const float2 g10 = tl[h10];
        const float2 g01 = tl[h01];
        const float2 g11 = tl[h11];
        const float w00 = (1.f - fx) * (1.f - fy);
        const float w10 = fx * (1.f - fy);
        const float w01 = (1.f - fx) * fy;
        const float w11 = fx * fy;
        feat[2 * l]     = g00.x * w00 + g10.x * w10 + g01.x * w01 + g11.x * w11;
        feat[2 * l + 1] = g00.y * w00 + g10.y * w10 + g01.y * w01 + g11.y * w11;
    }

    const f32x2* W0p = (const f32x2*)(weff + (size_t)b * WEFF_STRIDE);
    const f32x2* W1p = W0p + 512;
    const float* W2  = weff + (size_t)b * WEFF_STRIDE + 2048;

    f32x2 h1p[16];
    #pragma unroll
    for (int o2 = 0; o2 < 16; ++o2) {
        f32x2 acc; acc[0] = b0[o2]; acc[1] = b0[o2 + 16];
        #pragma unroll
        for (int i = 0; i < 32; ++i) {
            f32x2 fb; fb[0] = feat[i]; fb[1] = feat[i];
            acc += W0p[o2 * 32 + i] * fb;
        }
        acc[0] = fmaxf(acc[0], 0.f); acc[1] = fmaxf(acc[1], 0.f);
        h1p[o2] = acc;
    }
    f32x2 h2p[16];
    #pragma unroll
    for (int o2 = 0; o2 < 16; ++o2) {
        f32x2 acc; acc[0] = b1[o2]; acc[1] = b1[o2 + 16];
        #pragma unroll
        for (int i = 0; i < 32; ++i) {
            const float hv = h1p[i & 15][i >> 4];
            f32x2 fb; fb[0] = hv; fb[1] = hv;
            acc += W1p[o2 * 32 + i] * fb;
        }
        acc[0] = fmaxf(acc[0], 0.f); acc[1] = fmaxf(acc[1], 0.f);
        h2p[o2] = acc;
    }
    #pragma unroll
    for (int o = 0; o < 3; ++o) {
        float acc = b2[o];
        #pragma unroll
        for (int i = 0; i < 32; ++i)
            acc = fmaf(W2[o * 32 + i], h2p[i & 15][i >> 4], acc);
        out[((size_t)(b * 3 + o) << 16) + n] = tanhf(acc);
    }
}

// ---------------------------------------------------------------------------
extern "C" void kernel_launch(void* const* d_in, const int* in_sizes, int n_in,
                              void* d_out, int out_size, void* d_ws, size_t ws_size,
                              hipStream_t stream) {
    const float* x      = (const float*)d_in[0];
    const float* s      = (const float*)d_in[1];
    const float* coords = (const float*)d_in[2];
    const float* w0  = (const float*)d_in[3];
    const float* aw0 = (const float*)d_in[4];
    const float* ab0 = (const float*)d_in[5];
    const float* b0  = (const float*)d_in[6];
    const float* w1  = (const float*)d_in[7];
    const float* aw1 = (const float*)d_in[8];
    const float* ab1 = (const float*)d_in[9];
    const float* b1  = (const float*)d_in[10];
    const float* w2  = (const float*)d_in[11];
    const float* aw2 = (const float*)d_in[12];
    const float* ab2 = (const float*)d_in[13];
    const float* b2  = (const float*)d_in[14];
    float* out = (float*)d_out;
    float* ws  = (float*)d_ws;

    ResPack rp; OffPack op;
    int grid_tot = 0;
    const double g = pow(256.0 / 16.0, 1.0 / 15.0);
    for (int l = 0; l < LVL; ++l) {
        double r = 16.0 * pow(g, (double)l);
        long ri = lround(r);
        if (ri > 256) ri = 256;
        rp.r[l] = (int)ri;
        op.o[l] = grid_tot;
        grid_tot += (int)(ri * ri);
    }

    const size_t need = (size_t)GRIDS_OFF * 4 + (size_t)grid_tot * 8 * BATCH;

    hipLaunchKernelGGL(style_kernel, dim3(192), dim3(256), 0, stream,
                       s, aw0, ab0, aw1, ab1, aw2, ab2, ws);
    hipLaunchKernelGGL(weff_kernel, dim3(BATCH), dim3(256), 0, stream,
                       w0, w1, w2, ws);

    if (ws_size >= need) {
        float2* grids = (float2*)(ws + GRIDS_OFF);
        hipLaunchKernelGGL(grid_kernel, dim3(BATCH * LVL * (TBL / 256)), dim3(256), 0, stream,
                           x, grids, grid_tot, rp, op);
        hipLaunchKernelGGL(fused_kernel, dim3(NPIX / 256 * BATCH), dim3(256), 0, stream,
                           grids, coords, ws, b0, b1, b2, out, grid_tot, rp, op);
    } else {
        hipLaunchKernelGGL(fused_direct, dim3(NPIX / 256 * BATCH), dim3(256), 0, stream,
                           x, coords, ws, b0, b1, b2, out, rp);
    }
}

// Round 9
// 171.495 us; speedup vs baseline: 1.0259x; 1.0259x over previous
//
#include <hip/hip_runtime.h>
#include <math.h>

#define LVL 16
#define TBL 65536
#define BATCH 8
#define NPIX 65536       // 256*256
#define SDIM 512
#define HPRIME 2654435761u

typedef __attribute__((ext_vector_type(2))) float f32x2;

struct ResPack { int r[LVL]; };
struct OffPack { int o[LVL]; };   // per-level entry offset into dense grid (float2 units)
struct BlkPack { int o[LVL]; };   // per-level starting block within a batch (levels 0..14)
struct RcpPack { float f[LVL]; }; // 1.0f / R

// ws layout (floats): [0, 17152) weff (8 x 2144), [17152, 17920) style (8 x 96),
// [17920, ...) dense grids for levels 0..14: per batch grid_tot float2 entries.
#define WEFF_STRIDE 2144
#define STYLE_OFF   17152
#define GRIDS_OFF   17920    // floats; float2-aligned

// ---------------------------------------------------------------------------
// Kernel A1: style dots, one wave per (b, v). 768 waves.
// ---------------------------------------------------------------------------
__global__ __launch_bounds__(256) void style_kernel(
    const float* __restrict__ s,
    const float* __restrict__ aw0, const float* __restrict__ ab0,
    const float* __restrict__ aw1, const float* __restrict__ ab1,
    const float* __restrict__ aw2, const float* __restrict__ ab2,
    float* __restrict__ ws)
{
    const int wave_id = blockIdx.x * 4 + ((int)threadIdx.x >> 6);   // [0, 768)
    const int lane    = (int)threadIdx.x & 63;
    const int b = wave_id / 96;
    const int v = wave_id % 96;

    const float* row; float bias;
    if (v < 32)      { row = aw0 + v * SDIM;        bias = ab0[v]; }
    else if (v < 64) { row = aw1 + (v - 32) * SDIM; bias = ab1[v - 32]; }
    else             { row = aw2 + (v - 64) * SDIM; bias = ab2[v - 64]; }

    const float* sb = s + b * SDIM;
    float acc = 0.f;
    #pragma unroll
    for (int j = 0; j < SDIM / 64; ++j) {
        const int k = lane + j * 64;
        acc += sb[k] * row[k];
    }
    #pragma unroll
    for (int off = 32; off >= 1; off >>= 1) acc += __shfl_xor(acc, off, 64);
    if (lane == 0) ws[STYLE_OFF + b * 96 + v] = acc + bias;
}

// ---------------------------------------------------------------------------
// Kernel A2: demod + modulated weights, paired layout (round-7 verified).
// ---------------------------------------------------------------------------
__global__ __launch_bounds__(256) void weff_kernel(
    const float* __restrict__ w0, const float* __restrict__ w1, const float* __restrict__ w2,
    float* __restrict__ ws)
{
    const int b = blockIdx.x;
    __shared__ float st[96];
    __shared__ float demod[67];
    const int tid = (int)threadIdx.x;

    if (tid < 96) st[tid] = ws[STYLE_OFF + b * 96 + tid];
    __syncthreads();

    if (tid < 67) {
        const int o = tid;
        const float* wrow; const float* stp;
        if (o < 32)      { wrow = w0 + o * 32;        stp = st; }
        else if (o < 64) { wrow = w1 + (o - 32) * 32; stp = st + 32; }
        else             { wrow = w2 + (o - 64) * 32; stp = st + 64; }
        float sum = 0.f;
        #pragma unroll
        for (int i = 0; i < 32; ++i) { float v = wrow[i] * stp[i]; sum += v * v; }
        demod[o] = 1.0f / sqrtf(sum + 1e-8f);
    }
    __syncthreads();

    float* outp = ws + b * WEFF_STRIDE;
    for (int idx = tid; idx < 2144; idx += 256) {
        float v;
        if (idx < 1024) {
            const int o2 = idx >> 6, rem = idx & 63, i = rem >> 1, h = rem & 1;
            const int o = o2 + 16 * h;
            v = w0[o * 32 + i] * st[i] * demod[o];
        } else if (idx < 2048) {
            const int j = idx - 1024;
            const int o2 = j >> 6, rem = j & 63, i = rem >> 1, h = rem & 1;
            const int o = o2 + 16 * h;
            v = w1[o * 32 + i] * st[32 + i] * demod[32 + o];
        } else {
            const int j = idx - 2048; const int o = j >> 5, i = j & 31;
            v = w2[j] * st[64 + i] * demod[64 + o];
        }
        outp[idx] = v;
    }
}

// ---------------------------------------------------------------------------
// Kernel C: dense re-gridding for levels 0..14 only (level 15's hash window
// per row is already one aligned 2 KB span -> read direct in fused).
// Compact launch: exactly 8 * bpb blocks, zero dead blocks.
// y = idx/R via float-reciprocal: |err| <= 2.5e-5 < 0.5/R_max -> exact floor.
// ---------------------------------------------------------------------------
__global__ __launch_bounds__(256) void grid_kernel(
    const float* __restrict__ tables,   // [B, L, T, 2]
    float2* __restrict__ grids,         // [B][grid_tot]
    int grid_tot, int bpb,
    ResPack res, OffPack off, BlkPack blk, RcpPack rcp)
{
    const int bid  = (int)blockIdx.x;
    const int b    = bid / bpb;            // block-uniform scalar division
    const int lblk = bid - b * bpb;

    int l = 0;
    #pragma unroll
    for (int k = 1; k < 15; ++k) l += (lblk >= blk.o[k]) ? 1 : 0;

    const int R = res.r[l];
    const int idx = (lblk - blk.o[l]) * 256 + (int)threadIdx.x;
    if (idx >= R * R) return;

    const int y = (int)(((float)idx + 0.5f) * rcp.f[l]);
    const int x = idx - y * R;
    const unsigned h = ((unsigned)x ^ ((unsigned)y * HPRIME)) & 0xFFFFu;
    const float2* tl = (const float2*)(tables + ((size_t)b * LVL + l) * (TBL * 2));
    grids[(size_t)b * grid_tot + off.o[l] + idx] = tl[h];
}

// ---------------------------------------------------------------------------
// Kernel B: XCD-swizzled, 1 px/thread. Levels 0..14 from dense grids
// (no clamps: x1=x0+1, y1=y0+1 provably in-range), level 15 direct hash.
// Packed f32x2 interpolation; paired packed-fp32 MLP (round-7 verified).
// ---------------------------------------------------------------------------
__global__ __launch_bounds__(256) void fused_kernel(
    const float* __restrict__ tables,   // [B, L, T, 2] (level-15 direct reads)
    const float2* __restrict__ grids,   // [B][grid_tot] dense level grids
    const float* __restrict__ coords,   // [N, 2]
    const float* __restrict__ weff,     // ws: paired weights per batch
    const float* __restrict__ b0, const float* __restrict__ b1, const float* __restrict__ b2,
    float* __restrict__ out,            // [B, 3, 256, 256]
    int grid_tot, ResPack res, OffPack off)
{
    const int b     = blockIdx.x & 7;           // XCD-affinity: batch <-> XCD
    const int chunk = blockIdx.x >> 3;
    const int n     = chunk * 256 + (int)threadIdx.x;

    const float cx = coords[2 * n];
    const float cy = coords[2 * n + 1];
    const float2* gb = grids + (size_t)b * grid_tot;

    f32x2 feat2[16];

    #pragma unroll
    for (int l = 0; l < 15; ++l) {
        const int R = res.r[l];
        const float rm1 = (float)(R - 1);
        const float px = cx * rm1, py = cy * rm1;
        const float fpx = floorf(px), fpy = floorf(py);
        const float fx = px - fpx, fy = py - fpy;
        const int x0 = (int)fpx, y0 = (int)fpy;
        const float2* gl = gb + off.o[l];
        const int base = y0 * R + x0;
        const float2 g00 = gl[base];
        const float2 g10 = gl[base + 1];
        const float2 g01 = gl[base + R];
        const float2 g11 = gl[base + R + 1];
        const float w00 = (1.f - fx) * (1.f - fy);
        const float w10 = fx * (1.f - fy);
        const float w01 = (1.f - fx) * fy;
        const float w11 = fx * fy;
        f32x2 acc;
        acc[0] = g00.x * w00; acc[1] = g00.y * w00;
        acc[0] += g10.x * w10; acc[1] += g10.y * w10;
        acc[0] += g01.x * w01; acc[1] += g01.y * w01;
        acc[0] += g11.x * w11; acc[1] += g11.y * w11;
        feat2[l] = acc;
    }
    {   // level 15: R = 256, direct hash reads (row window = aligned 2 KB)
        const float rm1 = 255.f;
        const float px = cx * rm1, py = cy * rm1;
        const float fpx = floorf(px), fpy = floorf(py);
        const float fx = px - fpx, fy = py - fpy;
        const unsigned x0 = (unsigned)(int)fpx, y0 = (unsigned)(int)fpy;
        const unsigned hy0 = (y0 * HPRIME) & 0xFFFFu;
        const unsigned hy1 = ((y0 + 1u) * HPRIME) & 0xFFFFu;
        const float2* tl = (const float2*)(tables + ((size_t)b * LVL + 15) * (TBL * 2));
        const float2 g00 = tl[(x0 ^ hy0) & 0xFFFFu];
        const float2 g10 = tl[((x0 + 1u) ^ hy0) & 0xFFFFu];
        const float2 g01 = tl[(x0 ^ hy1) & 0xFFFFu];
        const float2 g11 = tl[((x0 + 1u) ^ hy1) & 0xFFFFu];
        const float w00 = (1.f - fx) * (1.f - fy);
        const float w10 = fx * (1.f - fy);
        const float w01 = (1.f - fx) * fy;
        const float w11 = fx * fy;
        f32x2 acc;
        acc[0] = g00.x * w00; acc[1] = g00.y * w00;
        acc[0] += g10.x * w10; acc[1] += g10.y * w10;
        acc[0] += g01.x * w01; acc[1] += g01.y * w01;
        acc[0] += g11.x * w11; acc[1] += g11.y * w11;
        feat2[15] = acc;
    }

    const f32x2* W0p = (const f32x2*)(weff + (size_t)b * WEFF_STRIDE);         // [16][32]
    const f32x2* W1p = W0p + 512;                                              // [16][32]
    const float* W2  = weff + (size_t)b * WEFF_STRIDE + 2048;                  // [3][32]
    const float* featf = (const float*)feat2;                                  // feat[32]

    f32x2 h1p[16];
    #pragma unroll
    for (int o2 = 0; o2 < 16; ++o2) {
        f32x2 acc; acc[0] = b0[o2]; acc[1] = b0[o2 + 16];
        #pragma unroll
        for (int i = 0; i < 32; ++i) {
            f32x2 fb; fb[0] = featf[i]; fb[1] = featf[i];
            acc += W0p[o2 * 32 + i] * fb;
        }
        acc[0] = fmaxf(acc[0], 0.f); acc[1] = fmaxf(acc[1], 0.f);
        h1p[o2] = acc;
    }

    f32x2 h2p[16];
    #pragma unroll
    for (int o2 = 0; o2 < 16; ++o2) {
        f32x2 acc; acc[0] = b1[o2]; acc[1] = b1[o2 + 16];
        #pragma unroll
        for (int i = 0; i < 32; ++i) {
            const float hv = h1p[i & 15][i >> 4];
            f32x2 fb; fb[0] = hv; fb[1] = hv;
            acc += W1p[o2 * 32 + i] * fb;
        }
        acc[0] = fmaxf(acc[0], 0.f); acc[1] = fmaxf(acc[1], 0.f);
        h2p[o2] = acc;
    }

    #pragma unroll
    for (int o = 0; o < 3; ++o) {
        float acc = b2[o];
        #pragma unroll
        for (int i = 0; i < 32; ++i)
            acc = fmaf(W2[o * 32 + i], h2p[i & 15][i >> 4], acc);
        out[((size_t)(b * 3 + o) << 16) + n] = tanhf(acc);
    }
}

// ---------------------------------------------------------------------------
// Fallback (round-7 verified): direct table reads, used only if ws too small.
// ---------------------------------------------------------------------------
__global__ __launch_bounds__(256) void fused_direct(
    const float* __restrict__ tables, const float* __restrict__ coords,
    const float* __restrict__ weff,
    const float* __restrict__ b0, const float* __restrict__ b1, const float* __restrict__ b2,
    float* __restrict__ out, ResPack res)
{
    const int b     = blockIdx.x & 7;
    const int chunk = blockIdx.x >> 3;
    const int n     = chunk * 256 + (int)threadIdx.x;
    const float cx = coords[2 * n];
    const float cy = coords[2 * n + 1];
    const float* tb = tables + (size_t)b * (LVL * TBL * 2);

    float feat[32];
    #pragma unroll
    for (int l = 0; l < LVL; ++l) {
        const int R = res.r[l];
        const float rm1 = (float)(R - 1);
        const float px = cx * rm1, py = cy * rm1;
        const float fpx = floorf(px), fpy = floorf(py);
        const float fx = px - fpx, fy = py - fpy;
        unsigned x0 = (unsigned)fpx, y0 = (unsigned)fpy;
        const unsigned hy0 = (y0 * HPRIME), hy1 = ((y0 + 1u) * HPRIME);
        const unsigned h00 = (x0 ^ hy0) & 0xFFFFu;
        const unsigned h10 = ((x0 + 1u) ^ hy0) & 0xFFFFu;
        const unsigned h01 = (x0 ^ hy1) & 0xFFFFu;
        const unsigned h11 = ((x0 + 1u) ^ hy1) & 0xFFFFu;
        const float2* tl = (const float2*)(tb + l * (TBL * 2));
        const float2 g00 = tl[h00];
        const float2 g10 = tl[h10];
        const float2 g01 = tl[h01];
        const float2 g11 = tl[h11];
        const float w00 = (1.f - fx) * (1.f - fy);
        const float w10 = fx * (1.f - fy);
        const float w01 = (1.f - fx) * fy;
        const float w11 = fx * fy;
        feat[2 * l]     = g00.x * w00 + g10.x * w10 + g01.x * w01 + g11.x * w11;
        feat[2 * l + 1] = g00.y * w00 + g10.y * w10 + g01.y * w01 + g11.y * w11;
    }

    const f32x2* W0p = (const f32x2*)(weff + (size_t)b * WEFF_STRIDE);
    const f32x2* W1p = W0p + 512;
    const float* W2  = weff + (size_t)b * WEFF_STRIDE + 2048;

    f32x2 h1p[16];
    #pragma unroll
    for (int o2 = 0; o2 < 16; ++o2) {
        f32x2 acc; acc[0] = b0[o2]; acc[1] = b0[o2 + 16];
        #pragma unroll
        for (int i = 0; i < 32; ++i) {
            f32x2 fb; fb[0] = feat[i]; fb[1] = feat[i];
            acc += W0p[o2 * 32 + i] * fb;
        }
        acc[0] = fmaxf(acc[0], 0.f); acc[1] = fmaxf(acc[1], 0.f);
        h1p[o2] = acc;
    }
    f32x2 h2p[16];
    #pragma unroll
    for (int o2 = 0; o2 < 16; ++o2) {
        f32x2 acc; acc[0] = b1[o2]; acc[1] = b1[o2 + 16];
        #pragma unroll
        for (int i = 0; i < 32; ++i) {
            const float hv = h1p[i & 15][i >> 4];
            f32x2 fb; fb[0] = hv; fb[1] = hv;
            acc += W1p[o2 * 32 + i] * fb;
        }
        acc[0] = fmaxf(acc[0], 0.f); acc[1] = fmaxf(acc[1], 0.f);
        h2p[o2] = acc;
    }
    #pragma unroll
    for (int o = 0; o < 3; ++o) {
        float acc = b2[o];
        #pragma unroll
        for (int i = 0; i < 32; ++i)
            acc = fmaf(W2[o * 32 + i], h2p[i & 15][i >> 4], acc);
        out[((size_t)(b * 3 + o) << 16) + n] = tanhf(acc);
    }
}

// ---------------------------------------------------------------------------
extern "C" void kernel_launch(void* const* d_in, const int* in_sizes, int n_in,
                              void* d_out, int out_size, void* d_ws, size_t ws_size,
                              hipStream_t stream) {
    const float* x      = (const float*)d_in[0];
    const float* s      = (const float*)d_in[1];
    const float* coords = (const float*)d_in[2];
    const float* w0  = (const float*)d_in[3];
    const float* aw0 = (const float*)d_in[4];
    const float* ab0 = (const float*)d_in[5];
    const float* b0  = (const float*)d_in[6];
    const float* w1  = (const float*)d_in[7];
    const float* aw1 = (const float*)d_in[8];
    const float* ab1 = (const float*)d_in[9];
    const float* b1  = (const float*)d_in[10];
    const float* w2  = (const float*)d_in[11];
    const float* aw2 = (const float*)d_in[12];
    const float* ab2 = (const float*)d_in[13];
    const float* b2  = (const float*)d_in[14];
    float* out = (float*)d_out;
    float* ws  = (float*)d_ws;

    ResPack rp; OffPack op; BlkPack bp; RcpPack cp;
    int grid_tot = 0, bpb = 0;
    const double g = pow(256.0 / 16.0, 1.0 / 15.0);
    for (int l = 0; l < LVL; ++l) {
        double r = 16.0 * pow(g, (double)l);
        long ri = lround(r);
        if (ri > 256) ri = 256;
        rp.r[l] = (int)ri;
        cp.f[l] = 1.0f / (float)ri;
        op.o[l] = grid_tot;
        bp.o[l] = bpb;
        if (l < 15) {
            grid_tot += (int)(ri * ri);
            bpb += (int)((ri * ri + 255) / 256);
        }
    }

    const size_t need = (size_t)GRIDS_OFF * 4 + (size_t)grid_tot * 8 * BATCH;

    hipLaunchKernelGGL(style_kernel, dim3(192), dim3(256), 0, stream,
                       s, aw0, ab0, aw1, ab1, aw2, ab2, ws);
    hipLaunchKernelGGL(weff_kernel, dim3(BATCH), dim3(256), 0, stream,
                       w0, w1, w2, ws);

    if (ws_size >= need) {
        float2* grids = (float2*)(ws + GRIDS_OFF);
        hipLaunchKernelGGL(grid_kernel, dim3(BATCH * bpb), dim3(256), 0, stream,
                           x, grids, grid_tot, bpb, rp, op, bp, cp);
        hipLaunchKernelGGL(fused_kernel, dim3(NPIX / 256 * BATCH), dim3(256), 0, stream,
                           x, grids, coords, ws, b0, b1, b2, out, grid_tot, rp, op);
    } else {
        hipLaunchKernelGGL(fused_direct, dim3(NPIX / 256 * BATCH), dim3(256), 0, stream,
                           x, coords, ws, b0, b1, b2, out, rp);
    }
}